// Round 11
// baseline (1772.219 us; speedup 1.0000x reference)
//
#include <hip/hip_runtime.h>

// VanillaLSTM v11 for MI355X (gfx950). N=2048, T=256, H=256, I=512, DOUT=5.
//
// v11 = v10 with the LDS-init race fixed. v10 failed POST-REPLAY revalidation:
// the h-buffer zero loop's second statement (from SM_HBL) overran into the xs
// staging region (and 512B past the smem array), racing with the x-chunk
// writes before the same barrier -> nondeterministic xs. One statement from
// SM_HBI covers both planes (contiguous 17408 B). Nothing else changed.
//
// v9 post-mortem: rec is VALU-issue-bound (VALUBusy 50%) + L2-latency on the
// G/O stream. v10/v11: cut VALU fat + hide stream latency; numerics unchanged.
//  - trailer table f32 (kills bf16 ull-unpack fat)
//  - pinned weights re-packed per-wave (all ds_read offsets immediate);
//    F_kt3 moved to stream (9 units/step, stream has 3x headroom)
//  - G0/O0/F3 stream loads issued during the IF phase; G/O 1-deep
//    consume-then-reload pipeline (regs <= ~60, no spill)
//  - packed xs [s][16][4] f32 (b128 reads); single-rint h-quant;
//    Hh t-major (carried store = 1 base + imm offsets)
//  - s-loop unrolled x2 (buffer parity compile-time)
// combo: blocks 0-127 rec chunk c, blocks 128-255 head chunk c-1 (dbl Hh).
//
// d_ws: [stream 144K][pinned 112K][trl f32 16K][W1 288K][state 4M][HhA][HhB]
//  stream: addr = wv*9216 + slot*1024 + l*16; slot 0..3=G_kt, 4..7=O_kt, 8=F3
//  pinned: addr = wv*7168 + (2*kt+cls)*1024 + l*16; cls 0=I,1=F (I0..3,F0..2)
//  i8 frag: col = q*256+wv*16+(l&15), k = kt*64+(l>>4)*16+e  (A same k-map)

typedef __attribute__((ext_vector_type(8))) short bf16x8;
typedef __attribute__((ext_vector_type(4))) float f32x4;
typedef __attribute__((ext_vector_type(4))) int   i32x4;
typedef unsigned long long ull;

#define HST 272
#define HBS 296
#define M1S 520
#define USHB 16384
#define HSOFF 2621440
#define CSOFF 3145728
#define I8S_OFF   0
#define I8P_OFF   147456
#define TRL_OFF   262144
#define W1_OFF    278528
#define WEIGHTS_B 573440ull
#define CSTATE_F  524288
#define STATE_B   4194304ull
#define H_OFF_B   (WEIGHTS_B + STATE_B)
// rec smem map
#define SM_PIN 0
#define SM_TRL 114688
#define SM_HBI 131072
#define SM_HBL 139776
#define SM_XS  148480
#define SM_TOTAL 156672
// head smem map
#define SM_AS 0
#define SM_M1 37888
#define SM_W2 104448

#define INVH 3.8750968e-6f   // 128/(16256*2032)
#define INVL 3.0274194e-8f   // 1/(16256*2032)

__device__ __forceinline__ unsigned short f2bf(float f) {
    unsigned u = __builtin_bit_cast(unsigned, f);
    u += 0x7fffu + ((u >> 16) & 1u);
    return (unsigned short)(u >> 16);
}
__device__ __forceinline__ float bf2f(unsigned short s) {
    unsigned u = ((unsigned)s) << 16;
    return __builtin_bit_cast(float, u);
}
__device__ __forceinline__ float sigm(float v)  { return 1.0f / (1.0f + __expf(-v)); }
__device__ __forceinline__ float tanh_(float v) { return 1.0f - 2.0f / (1.0f + __expf(2.0f * v)); }
__device__ __forceinline__ f32x4 MF(bf16x8 a, bf16x8 b, f32x4 c) {
    return __builtin_amdgcn_mfma_f32_16x16x32_bf16(a, b, c, 0, 0, 0);
}
__device__ __forceinline__ i32x4 MFI(i32x4 a, i32x4 b, i32x4 c) {
    return __builtin_amdgcn_mfma_i32_16x16x64_i8(a, b, c, 0, 0, 0);
}

// ---------------- prep: gate weights -> i8 (stream/pinned images) ----------------
__global__ void __launch_bounds__(1024) prep_gates_i8(
    const float* __restrict__ Whh, char* __restrict__ ws8)
{
    const int u = (int)blockIdx.x;       // q = u>>2 (0=i,1=f,2=g,3=o), kt = u&3
    const int q = u >> 2, kt = u & 3;
    const int tid = (int)threadIdx.x;
    const int wv = tid >> 6, l = tid & 63;
    size_t dst;
    if (q == 0)                 dst = (size_t)I8P_OFF + wv * 7168 + (2 * kt) * 1024;
    else if (q == 1 && kt < 3)  dst = (size_t)I8P_OFF + wv * 7168 + (2 * kt + 1) * 1024;
    else if (q == 1)            dst = (size_t)I8S_OFF + wv * 9216 + 8 * 1024;       // F3
    else if (q == 2)            dst = (size_t)I8S_OFF + wv * 9216 + kt * 1024;      // G
    else                        dst = (size_t)I8S_OFF + wv * 9216 + (4 + kt) * 1024;// O
    const int col = q * 256 + wv * 16 + (l & 15);
    const int kb  = kt * 64 + (l >> 4) * 16;
    union { char c[16]; i32x4 v; } p;
#pragma unroll
    for (int e = 0; e < 16; ++e) {
        float w = Whh[col * 256 + kb + e];
        int iq = (int)rintf(w * 2032.0f);
        iq = iq > 127 ? 127 : (iq < -127 ? -127 : iq);
        p.c[e] = (char)iq;
    }
    *(i32x4*)(ws8 + dst + l * 16) = p.v;
}

// ---------------- prep: trailer table f32 {w0,w1,w2,bias} per gate-col ----------------
__global__ void __launch_bounds__(1024) prep_trailer(
    const float* __restrict__ Wih, const float* __restrict__ bih,
    const float* __restrict__ bhh, char* __restrict__ ws8)
{
    const int col = (int)threadIdx.x;    // 0..1023
    float* t = (float*)(ws8 + TRL_OFF);
    t[col * 4 + 0] = Wih[col * 3 + 0];
    t[col * 4 + 1] = Wih[col * 3 + 1];
    t[col * 4 + 2] = Wih[col * 3 + 2];
    t[col * 4 + 3] = bih[col] + bhh[col];
}

// ---------------- prep: W1 bf16 units (head; b1 rides k=259) ----------------
__global__ void __launch_bounds__(1024) prep_w1(
    const float* __restrict__ W1, const float* __restrict__ b1,
    char* __restrict__ ws8)
{
    const int u = (int)blockIdx.x;       // 0..17: kt = u>>1, c5 = u&1
    const int kt = u >> 1, c5 = u & 1;
    const int tid = (int)threadIdx.x;
    const int wv = tid >> 6, l = tid & 63;
    const int lcol = l & 15, kgrp = l >> 4;
    const int col = wv * 32 + c5 * 16 + lcol;
    bf16x8 v;
#pragma unroll
    for (int e = 0; e < 8; ++e) {
        int k = kt * 32 + kgrp * 8 + e;
        float f = 0.f;
        if (k < 256)       f = W1[col * 256 + k];
        else if (k == 259) f = b1[col];
        v[e] = (short)f2bf(f);
    }
    *(bf16x8*)(ws8 + W1_OFF + (size_t)u * USHB + wv * 1024 + l * 16) = v;
}

// ---------------- combo: rec (blocks 0-127) + head chunk-1 (blocks 128-255) ----------------
__global__ void __launch_bounds__(1024)
combo(const float* __restrict__ x, const char* __restrict__ ws8,
      unsigned short* __restrict__ HhA, unsigned short* __restrict__ HhB,
      float* __restrict__ state, const float* __restrict__ W2,
      const float* __restrict__ b2, float* __restrict__ out,
      int t0, int tcl2)
{
    __shared__ __align__(16) char smem[SM_TOTAL];
    const int TC = 1 << tcl2;
    const int tid = (int)threadIdx.x;
    const int wv  = tid >> 6;
    const int l   = tid & 63;
    const int bid = (int)blockIdx.x;

    if (bid < 128) {
        // ================= recurrence, chunk [t0, t0+TC) =================
        if (t0 >= 256) return;
        unsigned short* Hh = ((t0 >> tcl2) & 1) ? HhB : HhA;
        const int n0   = bid * 16;
        const int r0   = (l >> 4) * 4;
        const int hcol = wv * 16 + (l & 15);

        // ---- init ----
        {   // pinned image -> LDS verbatim (114688 B)
            const i32x4* s4 = (const i32x4*)(ws8 + I8P_OFF);
            i32x4* d4 = (i32x4*)(smem + SM_PIN);
            for (int i = tid; i < 7168; i += 1024) d4[i] = s4[i];
        }
        {   // trailer f32 (16384 B)
            const ull* s8 = (const ull*)(ws8 + TRL_OFF);
            ull* d8 = (ull*)(smem + SM_TRL);
            d8[tid] = s8[tid]; d8[tid + 1024] = s8[tid + 1024];
        }
        // zero h planes: hbi+hbl are contiguous [SM_HBI, SM_HBI+17408).
        // (v10 BUG: a second statement from SM_HBL overran into SM_XS -> race.)
        for (int i = tid; i < 4352; i += 1024)
            ((int*)(smem + SM_HBI))[i] = 0;
        {   // x chunk -> packed LDS f32 [TC][16][4]
            float* xs = (float*)(smem + SM_XS);
            for (int i = tid; i < TC * 48; i += 1024) {
                int s = i / 48, rem = i - s * 48, r = rem / 3, d = rem - r * 3;
                xs[(s * 16 + r) * 4 + d] = x[(size_t)(n0 + r) * 768 + (size_t)(t0 + s) * 3 + d];
            }
        }
        __syncthreads();
        if (t0 > 0) {   // resume h (requant identical to in-loop path)
            for (int i = tid; i < 16 * 256; i += 1024) {
                int r = i >> 8, c = i & 255;
                float h = state[(size_t)(n0 + r) * 256 + c];
                int hq = (int)rintf(h * 16256.0f);
                int hi = (hq + 64) >> 7;
                smem[SM_HBI + r * HST + c] = (char)hi;
                smem[SM_HBL + r * HST + c] = (char)(hq - (hi << 7));
            }
        }
        float cst[4] = {0.f, 0.f, 0.f, 0.f};
        const size_t obase = (size_t)(n0 + r0) * 256 + hcol;
        if (t0 > 0) {
#pragma unroll
            for (int e = 0; e < 4; ++e) cst[e] = state[CSTATE_F + obase + (size_t)e * 256];
        }
        __syncthreads();

        // per-lane bases
        const unsigned hbiRd = SM_HBI + (unsigned)((l & 15) * HST + (l >> 4) * 16);
        const unsigned hblRd = SM_HBL + (unsigned)((l & 15) * HST + (l >> 4) * 16);
        const unsigned wrb   = SM_HBI + (unsigned)(r0 * HST + hcol);   // lo plane at +8704
        const unsigned pinb  = SM_PIN + (unsigned)(wv * 7168 + l * 16);
        const unsigned trlb  = SM_TRL + (unsigned)(hcol * 16);
        const char* gof = ws8 + I8S_OFF + wv * 9216 + l * 16;
        unsigned short* hhp = Hh + obase;                              // t-major: [t][n][col]
        float hvp[4] = {0.f, 0.f, 0.f, 0.f};

#define LDSI(off) (*(const i32x4*)(smem + (off)))
#define LDGI(off) (*(const i32x4*)(gof + (off)))
#define COLL(G, HA, LA, Q)                                                     \
        { f32x4 tv = *(const f32x4*)(smem + trlb + (Q) * 4096);                \
          _Pragma("unroll")                                                    \
          for (int e = 0; e < 4; ++e) {                                        \
              float T = tv[3] + xr[e][0]*tv[0] + xr[e][1]*tv[1] + xr[e][2]*tv[2]; \
              G[e] = (float)HA[e]*INVH + (float)LA[e]*INVL + T; } }

#define STEP(PAR)                                                              \
        {                                                                      \
            const int s = ss * 2 + (PAR);                                      \
            const int t = t0 + s;                                              \
            /* (a) carried Hh store for step s-1 */                            \
            if (s > 0) {                                                       \
                hhp[0]   = f2bf(hvp[0]); hhp[256] = f2bf(hvp[1]);              \
                hhp[512] = f2bf(hvp[2]); hhp[768] = f2bf(hvp[3]);              \
                hhp += 524288;                                                 \
            }                                                                  \
            /* (b) early stream issues: F3, G0, O0 */                          \
            i32x4 wf3 = LDGI(8192);                                            \
            i32x4 wg  = LDGI(0);                                               \
            i32x4 wo  = LDGI(4096);                                            \
            /* (c) IF phase: pinned LDS weights */                             \
            i32x4 z = {0,0,0,0};                                               \
            i32x4 hI = z, lI = z, hF = z, lF = z;                              \
            _Pragma("unroll")                                                  \
            for (int kt = 0; kt < 4; ++kt) {                                   \
                i32x4 ah = LDSI(hbiRd + (PAR)*4352 + kt*64);                   \
                i32x4 al = LDSI(hblRd + (PAR)*4352 + kt*64);                   \
                i32x4 wi = LDSI(pinb + kt*2048);                               \
                i32x4 wf = (kt < 3) ? LDSI(pinb + kt*2048 + 1024) : wf3;       \
                hI = MFI(ah, wi, hI);  lI = MFI(al, wi, lI);                   \
                hF = MFI(ah, wf, hF);  lF = MFI(al, wf, lF);                   \
            }                                                                  \
            /* (d) collapse I,F */                                             \
            float iv[4], fv[4];                                                \
            {                                                                  \
                f32x4 xr[4];                                                   \
                _Pragma("unroll")                                              \
                for (int e = 0; e < 4; ++e)                                    \
                    xr[e] = *(const f32x4*)(smem + SM_XS + s*256 + r0*16 + e*16); \
                float gI_[4], gF_[4];                                          \
                COLL(gI_, hI, lI, 0)                                           \
                COLL(gF_, hF, lF, 1)                                           \
                _Pragma("unroll")                                              \
                for (int e = 0; e < 4; ++e) { iv[e] = sigm(gI_[e]); fv[e] = sigm(gF_[e]); } \
            }                                                                  \
            /* (e) GO phase: streamed, 1-deep reload pipeline */               \
            i32x4 hG = z, lG = z, hO = z, lO = z;                              \
            _Pragma("unroll")                                                  \
            for (int kt = 0; kt < 4; ++kt) {                                   \
                i32x4 ah = LDSI(hbiRd + (PAR)*4352 + kt*64);                   \
                i32x4 al = LDSI(hblRd + (PAR)*4352 + kt*64);                   \
                hG = MFI(ah, wg, hG);  lG = MFI(al, wg, lG);                   \
                if (kt < 3) wg = LDGI((kt+1)*1024);                            \
                hO = MFI(ah, wo, hO);  lO = MFI(al, wo, lO);                   \
                if (kt < 3) wo = LDGI(4096 + (kt+1)*1024);                     \
            }                                                                  \
            /* (f) collapse G,O */                                             \
            float gv[4], ov[4];                                                \
            {                                                                  \
                f32x4 xr[4];                                                   \
                _Pragma("unroll")                                              \
                for (int e = 0; e < 4; ++e)                                    \
                    xr[e] = *(const f32x4*)(smem + SM_XS + s*256 + r0*16 + e*16); \
                float gG_[4], gO_[4];                                          \
                COLL(gG_, hG, lG, 2)                                           \
                COLL(gO_, hO, lO, 3)                                           \
                _Pragma("unroll")                                              \
                for (int e = 0; e < 4; ++e) { gv[e] = tanh_(gG_[e]); ov[e] = sigm(gO_[e]); } \
            }                                                                  \
            /* (g) cell update + quantized h write + tails */                  \
            _Pragma("unroll")                                                  \
            for (int e = 0; e < 4; ++e) {                                      \
                float cv = fv[e] * cst[e] + iv[e] * gv[e];                     \
                cst[e] = cv;                                                   \
                float hv = ov[e] * tanh_(cv);                                  \
                hvp[e] = hv;                                                   \
                int hq = (int)rintf(hv * 16256.0f);                            \
                int hi = (hq + 64) >> 7;                                       \
                smem[wrb + (((PAR)^1)*4352 + e*HST)]        = (char)hi;        \
                smem[wrb + (8704 + ((PAR)^1)*4352 + e*HST)] = (char)(hq - (hi << 7)); \
                if (t == 255) {                                                \
                    out[HSOFF + obase + (size_t)e * 256] = hv;                 \
                    out[CSOFF + obase + (size_t)e * 256] = cv;                 \
                } else if (s == TC - 1) {                                      \
                    state[obase + (size_t)e * 256] = hv;                       \
                    state[CSTATE_F + obase + (size_t)e * 256] = cv;            \
                }                                                              \
            }                                                                  \
            __syncthreads();                                                   \
        }

#pragma clang loop unroll(disable)
        for (int ss = 0; ss < TC / 2; ++ss) {
            STEP(0)
            STEP(1)
        }
        // final Hh slot (s = TC-1)
        hhp[0]   = f2bf(hvp[0]); hhp[256] = f2bf(hvp[1]);
        hhp[512] = f2bf(hvp[2]); hhp[768] = f2bf(hvp[3]);
#undef STEP
#undef COLL
#undef LDSI
#undef LDGI
    } else {
        // ================= head for chunk [t0-TC, t0), Hh t-major =================
        if (t0 == 0) return;
        const unsigned short* Hh = (((t0 >> tcl2) & 1) ^ 1) ? HhB : HhA;
        const int t0p = t0 - TC;
        unsigned short* As  = (unsigned short*)(smem + SM_AS);   // [64][HBS]
        unsigned short* m1s = (unsigned short*)(smem + SM_M1);   // [64][M1S]
        unsigned short* w2s = (unsigned short*)(smem + SM_W2);   // [5*512]
        const int lcol = l & 15, kgrp = l >> 4;
        const int laneoff_b = wv * 1024 + l * 16;
        const char* w1u = ws8 + W1_OFF;

        for (int i = tid; i < 5 * 512; i += 1024) w2s[i] = f2bf(W2[i]);

        const int ntiles = TC >> 2;          // (2048*TC/64)/128
        for (int it = 0; it < ntiles; ++it) {
            const size_t tok0 = ((size_t)(bid - 128) + (size_t)it * 128) * 64;
            __syncthreads();                 // protect As/m1s from prev tile
            for (int i = tid; i < 2048; i += 1024) {
                int tr = i >> 5, c8 = (i & 31) * 8;
                *(bf16x8*)(&As[tr * HBS + c8]) = *(const bf16x8*)(&Hh[(tok0 + tr) * 256 + c8]);
            }
            for (int i = tid; i < 64 * 40; i += 1024) {
                int tr = i / 40, c = 256 + i % 40;
                As[tr * HBS + c] = (c == 259) ? (unsigned short)0x3F80 : (unsigned short)0;
            }
            __syncthreads();

            const char* sp = w1u + laneoff_b;
            const int arow_b = ((l & 15) * HBS + kgrp * 8) * 2;
            const char* Asb = (const char*)As;
            f32x4 a0[4], a1[4];
#pragma unroll
            for (int mt = 0; mt < 4; ++mt) { a0[mt] = (f32x4){0,0,0,0}; a1[mt] = (f32x4){0,0,0,0}; }
#pragma clang loop unroll(disable)
            for (int kt = 0; kt < 9; ++kt) {
                bf16x8 b4 = *(const bf16x8*)sp;
                bf16x8 b5 = *(const bf16x8*)(sp + USHB);
                sp += 2 * USHB;
#pragma unroll
                for (int mt = 0; mt < 4; ++mt) {
                    bf16x8 av = *(const bf16x8*)(Asb + arow_b + mt * (16 * HBS * 2) + kt * 64);
                    a0[mt] = MF(av, b4, a0[mt]);
                    a1[mt] = MF(av, b5, a1[mt]);
                }
            }
            const int r0h = (l >> 4) * 4, m0c = wv * 32 + lcol, m1c = wv * 32 + 16 + lcol;
#pragma unroll
            for (int mt = 0; mt < 4; ++mt)
#pragma unroll
                for (int e = 0; e < 4; ++e) {
                    int tr = mt * 16 + r0h + e;
                    m1s[tr * M1S + m0c] = f2bf(a0[mt][e] > 0.f ? a0[mt][e] : 0.f);
                    m1s[tr * M1S + m1c] = f2bf(a1[mt][e] > 0.f ? a1[mt][e] : 0.f);
                }
            __syncthreads();

            const int grp = tid >> 3, pl = tid & 7;
            const int gn = grp / 5, gj = grp - gn * 5;
            if (tid < 640) {
                float b2r = b2[gj];
                for (int rd = 0; rd < 4; ++rd) {
                    int tr = rd * 16 + gn;
                    float acc = 0.f;
#pragma unroll
                    for (int q = 0; q < 8; ++q) {
                        bf16x8 mv  = *(const bf16x8*)(&m1s[tr * M1S] + q * 64 + pl * 8);
                        bf16x8 wvv = *(const bf16x8*)(&w2s[gj * 512] + q * 64 + pl * 8);
#pragma unroll
                        for (int e = 0; e < 8; ++e)
                            acc += bf2f((unsigned short)mv[e]) * bf2f((unsigned short)wvv[e]);
                    }
                    acc += __shfl_xor(acc, 1);
                    acc += __shfl_xor(acc, 2);
                    acc += __shfl_xor(acc, 4);
                    if (pl == 0) {
                        size_t tok = tok0 + tr;       // t-major: tok = tloc*2048 + n
                        int n    = (int)(tok & 2047);
                        int tloc = (int)(tok >> 11);
                        out[(size_t)n * 1280 + (size_t)(t0p + tloc) * 5 + gj] = acc + b2r;
                    }
                }
            }
        }
    }
}

extern "C" void kernel_launch(void* const* d_in, const int* in_sizes, int n_in,
                              void* d_out, int out_size, void* d_ws, size_t ws_size,
                              hipStream_t stream) {
    (void)in_sizes; (void)n_in; (void)out_size;
    const float* x   = (const float*)d_in[0];
    const float* Wih = (const float*)d_in[1];
    const float* Whh = (const float*)d_in[2];
    const float* bih = (const float*)d_in[3];
    const float* bhh = (const float*)d_in[4];
    const float* W1  = (const float*)d_in[5];
    const float* b1  = (const float*)d_in[6];
    const float* W2  = (const float*)d_in[7];
    const float* b2  = (const float*)d_in[8];
    char* ws8 = (char*)d_ws;
    float* o = (float*)d_out;

    prep_gates_i8<<<16, 1024, 0, stream>>>(Whh, ws8);
    prep_trailer<<<1, 1024, 0, stream>>>(Wih, bih, bhh, ws8);
    prep_w1<<<18, 1024, 0, stream>>>(W1, b1, ws8);

    // TC tier: need H_OFF_B + 2 * (2048*TC*256*2) bytes (v9 proved ws >= 72MB).
    int tcl2 = (ws_size >= H_OFF_B + 2ull * 2048ull * 32ull * 256ull * 2ull) ? 5 : 4;
    const int TC = 1 << tcl2;
    float* state = (float*)(ws8 + WEIGHTS_B);
    unsigned short* HhA = (unsigned short*)(ws8 + H_OFF_B);
    unsigned short* HhB = HhA + (size_t)2048 * TC * 256;

    for (int t0 = 0; t0 <= 256; t0 += TC)
        combo<<<256, 1024, 0, stream>>>(x, ws8, HhA, HhB, state, W2, b2, o, t0, tcl2);
}

// Round 12
// 1249.119 us; speedup vs baseline: 1.4188x; 1.4188x over previous
//
#include <hip/hip_runtime.h>

// VanillaLSTM v12 for MI355X (gfx950). N=2048, T=256, H=256, I=512, DOUT=5.
//
// v11 post-mortem: v10/v11's restructure (x2 unrolled STEP, triple early
// issue) tipped past the fixed 64-VGPR budget -> in-loop spills returned
// (FETCH 23->57 MB, WRITE +26 MB, rec 168->229 us). v12 reverts to v9's
// proven structure EXACTLY and applies only register-neutral VALU cuts:
//   - int-combine collapse: G = (float)((hI<<7)+lI)*INVL + T
//     (one lshl+add+cvt replaces 2 cvt + mul + fma per element)
//   - single-rint h-quant: hq=rint(16256h); hi=(hq+64)>>7; lo=hq-128*hi
//     (same dual-i8 reconstruction domain; resume path matches)
// Everything else = v9: rolled s-loop w/ runtime parity, v9 stream/pinned
// layout, bf16 trailer table, n-major Hh, combo split rec|head, dbl Hh.
//
// d_ws: [i8 stream 128K][i8 pinned 128K][trailer 16K][W1 bf16 288K]
//       [state h,c f32 4MB][HhA][HhB]
// i8 unit (q,kt): ws[off + wv*1KB + lane*16B] = 16 i8, col=q*256+wv*16+(l&15),
//   k = kt*64 + (l>>4)*16 + e.  A-side identical (lane,e)->k map -> cancels.

typedef __attribute__((ext_vector_type(8))) short bf16x8;
typedef __attribute__((ext_vector_type(4))) float f32x4;
typedef __attribute__((ext_vector_type(4))) int   i32x4;
typedef unsigned long long ull;

#define ROWS 16
#define HST 272
#define HBS 296
#define M1S 520
#define USHB 16384
#define HSOFF 2621440
#define CSOFF 3145728
#define I8S_OFF   0
#define I8P_OFF   131072
#define TRL_OFF   262144
#define W1_OFF    278528
#define WEIGHTS_B 573440ull
#define CSTATE_F  524288
#define STATE_B   4194304ull
#define H_OFF_B   (WEIGHTS_B + STATE_B)
// rec smem map
#define SM_PIN 0
#define SM_TRL 131072
#define SM_HBI 139264
#define SM_HBL 147968
#define SM_XS  156672
#define SM_TOTAL 162816
// head smem map
#define SM_AS 0
#define SM_M1 37888
#define SM_W2 104448

#define INVL 3.027358e-8f    // 1/(16256*2032)

__device__ __forceinline__ unsigned short f2bf(float f) {
    unsigned u = __builtin_bit_cast(unsigned, f);
    u += 0x7fffu + ((u >> 16) & 1u);
    return (unsigned short)(u >> 16);
}
__device__ __forceinline__ float bf2f(unsigned short s) {
    unsigned u = ((unsigned)s) << 16;
    return __builtin_bit_cast(float, u);
}
__device__ __forceinline__ float sigm(float v)  { return 1.0f / (1.0f + __expf(-v)); }
__device__ __forceinline__ float tanh_(float v) { return 1.0f - 2.0f / (1.0f + __expf(2.0f * v)); }
__device__ __forceinline__ f32x4 MF(bf16x8 a, bf16x8 b, f32x4 c) {
    return __builtin_amdgcn_mfma_f32_16x16x32_bf16(a, b, c, 0, 0, 0);
}
__device__ __forceinline__ i32x4 MFI(i32x4 a, i32x4 b, i32x4 c) {
    return __builtin_amdgcn_mfma_i32_16x16x64_i8(a, b, c, 0, 0, 0);
}

// ---------------- prep: gate weights -> i8 units ----------------
__global__ void __launch_bounds__(1024) prep_gates_i8(
    const float* __restrict__ Whh, char* __restrict__ ws8)
{
    const int u = (int)blockIdx.x;       // q = u>>2 (0=i,1=f,2=g,3=o), kt = u&3
    const int q = u >> 2, kt = u & 3;
    const int tid = (int)threadIdx.x;
    const int wv = tid >> 6, l = tid & 63;
    size_t off = (q >= 2) ? (size_t)I8S_OFF + (size_t)(kt * 2 + (q - 2)) * USHB
                          : (size_t)I8P_OFF + (size_t)(kt * 2 + q) * USHB;
    const int col = q * 256 + wv * 16 + (l & 15);
    const int kb  = kt * 64 + (l >> 4) * 16;
    union { char c[16]; i32x4 v; } p;
#pragma unroll
    for (int e = 0; e < 16; ++e) {
        float w = Whh[col * 256 + kb + e];
        int iq = (int)rintf(w * 2032.0f);
        iq = iq > 127 ? 127 : (iq < -127 ? -127 : iq);
        p.c[e] = (char)iq;
    }
    *(i32x4*)(ws8 + off + wv * 1024 + l * 16) = p.v;
}

// ---------------- prep: trailer table (W_ih + gate bias, bf16) ----------------
__global__ void __launch_bounds__(1024) prep_trailer(
    const float* __restrict__ Wih, const float* __restrict__ bih,
    const float* __restrict__ bhh, char* __restrict__ ws8)
{
    const int col = (int)threadIdx.x;    // 0..1023
    unsigned short* t = (unsigned short*)(ws8 + TRL_OFF);
    t[col * 4 + 0] = f2bf(Wih[col * 3 + 0]);
    t[col * 4 + 1] = f2bf(Wih[col * 3 + 1]);
    t[col * 4 + 2] = f2bf(Wih[col * 3 + 2]);
    t[col * 4 + 3] = f2bf(bih[col] + bhh[col]);
}

// ---------------- prep: W1 bf16 units (head; b1 rides k=259) ----------------
__global__ void __launch_bounds__(1024) prep_w1(
    const float* __restrict__ W1, const float* __restrict__ b1,
    char* __restrict__ ws8)
{
    const int u = (int)blockIdx.x;       // 0..17: kt = u>>1, c5 = u&1
    const int kt = u >> 1, c5 = u & 1;
    const int tid = (int)threadIdx.x;
    const int wv = tid >> 6, l = tid & 63;
    const int lcol = l & 15, kgrp = l >> 4;
    const int col = wv * 32 + c5 * 16 + lcol;
    bf16x8 v;
#pragma unroll
    for (int e = 0; e < 8; ++e) {
        int k = kt * 32 + kgrp * 8 + e;
        float f = 0.f;
        if (k < 256)       f = W1[col * 256 + k];
        else if (k == 259) f = b1[col];
        v[e] = (short)f2bf(f);
    }
    *(bf16x8*)(ws8 + W1_OFF + (size_t)u * USHB + wv * 1024 + l * 16) = v;
}

// ---------------- combo: rec (blocks 0-127) + head chunk-1 (blocks 128-255) ----------------
__global__ void __launch_bounds__(1024)
combo(const float* __restrict__ x, const char* __restrict__ ws8,
      unsigned short* __restrict__ HhA, unsigned short* __restrict__ HhB,
      float* __restrict__ state, const float* __restrict__ W2,
      const float* __restrict__ b2, float* __restrict__ out,
      int t0, int tcl2)
{
    __shared__ __align__(16) char smem[SM_TOTAL];
    const int TC = 1 << tcl2;
    const int tid = (int)threadIdx.x;
    const int wv  = tid >> 6;
    const int l   = tid & 63;
    const int bid = (int)blockIdx.x;

    if (bid < 128) {
        // ================= recurrence, chunk [t0, t0+TC) =================
        if (t0 >= 256) return;
        unsigned short* Hh = ((t0 >> tcl2) & 1) ? HhB : HhA;
        const int n0   = bid * 16;
        const int r0   = (l >> 4) * 4;
        const int hcol = wv * 16 + (l & 15);
        const int xw   = TC * 3;

        // ---- init ----
        {   // pinned I,F units (128 KB)
            const i32x4* s4 = (const i32x4*)(ws8 + I8P_OFF);
            i32x4* d4 = (i32x4*)(smem + SM_PIN);
            for (int i = tid; i < 8192; i += 1024) d4[i] = s4[i];
        }
        ((ull*)(smem + SM_TRL))[tid] = ((const ull*)(ws8 + TRL_OFF))[tid];
        // zero BOTH h planes: [SM_HBI, SM_HBI+17408) covers hbi+hbl (contiguous)
        for (int i = tid; i < 4352; i += 1024)
            ((int*)(smem + SM_HBI))[i] = 0;
        {   // x chunk -> LDS f32 [16][TC*3]
            float* xs = (float*)(smem + SM_XS);
            for (int i = tid; i < 16 * xw; i += 1024) {
                int r = i / xw, c = i - r * xw;
                xs[i] = x[(size_t)(n0 + r) * 768 + (size_t)t0 * 3 + c];
            }
        }
        __syncthreads();
        if (t0 > 0) {   // resume h (requant identical to in-loop path)
            for (int i = tid; i < 16 * 256; i += 1024) {
                int r = i >> 8, c = i & 255;
                float h = state[(size_t)(n0 + r) * 256 + c];
                int hq = (int)rintf(h * 16256.0f);
                int hi = (hq + 64) >> 7;
                smem[SM_HBI + r * HST + c] = (char)hi;
                smem[SM_HBL + r * HST + c] = (char)(hq - (hi << 7));
            }
        }
        float cst[4] = {0.f, 0.f, 0.f, 0.f};
        const size_t obase = (size_t)(n0 + r0) * 256 + hcol;
        if (t0 > 0) {
#pragma unroll
            for (int e = 0; e < 4; ++e) cst[e] = state[CSTATE_F + obase + (size_t)e * 256];
        }
        __syncthreads();

        // hoisted bases (v9 structure: running pointers, runtime parity)
        const char* lwI = smem + SM_PIN + wv * 1024 + l * 16;          // I @ kt*2*USHB
        const char* gpt = ws8 + I8S_OFF + wv * 1024 + l * 16;          // G @ kt*2*USHB
        const char* hA0 = smem + SM_HBI + (l & 15) * HST + (l >> 4) * 16;
        const char* hL0 = smem + SM_HBL + (l & 15) * HST + (l >> 4) * 16;
        char*       wH0 = smem + SM_HBI + r0 * HST + hcol;
        const unsigned short* trl = (const unsigned short*)(smem + SM_TRL);
        const float* xs = (const float*)(smem + SM_XS);
        const size_t hqb = (size_t)(n0 + r0) * TC * 256 + hcol;
        const int eo = TC * 256;
        float hvp[4] = {0.f, 0.f, 0.f, 0.f};

#define COLLAPSE(G, HR, LR, Q)                                                \
        { ull tv = *(const ull*)(trl + ((Q) * 256 + hcol) * 4);               \
          float w0 = bf2f((unsigned short)tv);                                \
          float w1 = bf2f((unsigned short)(tv >> 16));                        \
          float w2 = bf2f((unsigned short)(tv >> 32));                        \
          float bb = bf2f((unsigned short)(tv >> 48));                        \
          _Pragma("unroll")                                                   \
          for (int e = 0; e < 4; ++e)                                         \
              G[e] = (float)((HR[e] << 7) + LR[e]) * INVL                     \
                     + xr0[e] * w0 + xr1[e] * w1 + xr2[e] * w2 + bb; }

#pragma clang loop unroll(disable)
        for (int s = 0; s < TC; ++s) {
            const int par = s & 1;
            const int t = t0 + s;
            const char* hA = hA0 + par * 4352;
            const char* hL = hL0 + par * 4352;
            char*       wH = wH0 + (par ^ 1) * 4352;

            // (a) store previous step's h to Hh (drains overlapped with this step)
            if (s > 0) {
                size_t b = hqb + (size_t)(s - 1) * 256;
                Hh[b]          = f2bf(hvp[0]);
                Hh[b + eo]     = f2bf(hvp[1]);
                Hh[b + 2 * eo] = f2bf(hvp[2]);
                Hh[b + 3 * eo] = f2bf(hvp[3]);
            }

            // (b) prefetch first two G/O stream pairs
            i32x4 wg0 = *(const i32x4*)(gpt);
            i32x4 wo0 = *(const i32x4*)(gpt + USHB);
            i32x4 wg1 = *(const i32x4*)(gpt + 2 * USHB);
            i32x4 wo1 = *(const i32x4*)(gpt + 3 * USHB);

            // (c) {I,F} pass: pinned LDS, kt unrolled
            i32x4 z = {0, 0, 0, 0};
            i32x4 hI = z, lI = z, hF = z, lF = z;
#pragma unroll
            for (int kt = 0; kt < 4; ++kt) {
                i32x4 ah = *(const i32x4*)(hA + kt * 64);
                i32x4 al = *(const i32x4*)(hL + kt * 64);
                i32x4 wi = *(const i32x4*)(lwI + (2 * kt) * USHB);
                i32x4 wf = *(const i32x4*)(lwI + (2 * kt + 1) * USHB);
                hI = MFI(ah, wi, hI);  lI = MFI(al, wi, lI);
                hF = MFI(ah, wf, hF);  lF = MFI(al, wf, lF);
            }

            // (d) x row values for trailer
            float xr0[4], xr1[4], xr2[4];
#pragma unroll
            for (int e = 0; e < 4; ++e) {
                const float* xp = xs + (r0 + e) * xw + s * 3;
                xr0[e] = xp[0]; xr1[e] = xp[1]; xr2[e] = xp[2];
            }

            // (e) collapse I,F + trailer + sigmoid
            float gI_[4], gF_[4], iv[4], fv[4];
            COLLAPSE(gI_, hI, lI, 0)
            COLLAPSE(gF_, hF, lF, 1)
#pragma unroll
            for (int e = 0; e < 4; ++e) { iv[e] = sigm(gI_[e]); fv[e] = sigm(gF_[e]); }

            // (f) {G,O} pass: streamed L2, kt unrolled, 2-deep ping-pong
            i32x4 hG = z, lG = z, hO = z, lO = z;
            i32x4 wg2 = *(const i32x4*)(gpt + 4 * USHB);
            i32x4 wo2 = *(const i32x4*)(gpt + 5 * USHB);
            {
                i32x4 ah = *(const i32x4*)(hA);
                i32x4 al = *(const i32x4*)(hL);
                hG = MFI(ah, wg0, hG);  lG = MFI(al, wg0, lG);
                hO = MFI(ah, wo0, hO);  lO = MFI(al, wo0, lO);
            }
            i32x4 wg3 = *(const i32x4*)(gpt + 6 * USHB);
            i32x4 wo3 = *(const i32x4*)(gpt + 7 * USHB);
            {
                i32x4 ah = *(const i32x4*)(hA + 64);
                i32x4 al = *(const i32x4*)(hL + 64);
                hG = MFI(ah, wg1, hG);  lG = MFI(al, wg1, lG);
                hO = MFI(ah, wo1, hO);  lO = MFI(al, wo1, lO);
            }
            {
                i32x4 ah = *(const i32x4*)(hA + 128);
                i32x4 al = *(const i32x4*)(hL + 128);
                hG = MFI(ah, wg2, hG);  lG = MFI(al, wg2, lG);
                hO = MFI(ah, wo2, hO);  lO = MFI(al, wo2, lO);
            }
            {
                i32x4 ah = *(const i32x4*)(hA + 192);
                i32x4 al = *(const i32x4*)(hL + 192);
                hG = MFI(ah, wg3, hG);  lG = MFI(al, wg3, lG);
                hO = MFI(ah, wo3, hO);  lO = MFI(al, wo3, lO);
            }

            // (g) collapse G,O + activations
            float gG_[4], gO_[4], gv[4], ov[4];
            COLLAPSE(gG_, hG, lG, 2)
            COLLAPSE(gO_, hO, lO, 3)
#pragma unroll
            for (int e = 0; e < 4; ++e) { gv[e] = tanh_(gG_[e]); ov[e] = sigm(gO_[e]); }

            // (h) cell update, single-rint quantized h write, tails
#pragma unroll
            for (int e = 0; e < 4; ++e) {
                float cv = fv[e] * cst[e] + iv[e] * gv[e];
                cst[e] = cv;
                float hv = ov[e] * tanh_(cv);
                hvp[e] = hv;
                int hq = (int)rintf(hv * 16256.0f);
                int hi = (hq + 64) >> 7;
                wH[e * HST]        = (char)hi;
                wH[e * HST + 8704] = (char)(hq - (hi << 7));
                if (t == 255) {
                    out[HSOFF + obase + (size_t)e * 256] = hv;
                    out[CSOFF + obase + (size_t)e * 256] = cv;
                } else if (s == TC - 1) {
                    state[obase + (size_t)e * 256] = hv;
                    state[CSTATE_F + obase + (size_t)e * 256] = cv;
                }
            }
            __syncthreads();
        }
        // final Hh slot (s = TC-1)
        {
            size_t b = hqb + (size_t)(TC - 1) * 256;
            Hh[b]          = f2bf(hvp[0]);
            Hh[b + eo]     = f2bf(hvp[1]);
            Hh[b + 2 * eo] = f2bf(hvp[2]);
            Hh[b + 3 * eo] = f2bf(hvp[3]);
        }
#undef COLLAPSE
    } else {
        // ================= head for chunk [t0-TC, t0) =================
        if (t0 == 0) return;
        const unsigned short* Hh = (((t0 >> tcl2) & 1) ^ 1) ? HhB : HhA;
        const int t0p = t0 - TC;
        unsigned short* As  = (unsigned short*)(smem + SM_AS);   // [64][HBS]
        unsigned short* m1s = (unsigned short*)(smem + SM_M1);   // [64][M1S]
        unsigned short* w2s = (unsigned short*)(smem + SM_W2);   // [5*512]
        const int lcol = l & 15, kgrp = l >> 4;
        const int laneoff_b = wv * 1024 + l * 16;
        const char* w1u = ws8 + W1_OFF;

        for (int i = tid; i < 5 * 512; i += 1024) w2s[i] = f2bf(W2[i]);

        const int ntiles = TC >> 2;          // (2048*TC/64)/128
        for (int it = 0; it < ntiles; ++it) {
            const size_t tok0 = ((size_t)(bid - 128) + (size_t)it * 128) * 64;
            __syncthreads();                 // protect As/m1s from prev tile
            for (int i = tid; i < 2048; i += 1024) {
                int tr = i >> 5, c8 = (i & 31) * 8;
                *(bf16x8*)(&As[tr * HBS + c8]) = *(const bf16x8*)(&Hh[(tok0 + tr) * 256 + c8]);
            }
            for (int i = tid; i < 64 * 40; i += 1024) {
                int tr = i / 40, c = 256 + i % 40;
                As[tr * HBS + c] = (c == 259) ? (unsigned short)0x3F80 : (unsigned short)0;
            }
            __syncthreads();

            const char* sp = w1u + laneoff_b;
            const int arow_b = ((l & 15) * HBS + kgrp * 8) * 2;
            const char* Asb = (const char*)As;
            f32x4 a0[4], a1[4];
#pragma unroll
            for (int mt = 0; mt < 4; ++mt) { a0[mt] = (f32x4){0,0,0,0}; a1[mt] = (f32x4){0,0,0,0}; }
#pragma clang loop unroll(disable)
            for (int kt = 0; kt < 9; ++kt) {
                bf16x8 b4 = *(const bf16x8*)sp;
                bf16x8 b5 = *(const bf16x8*)(sp + USHB);
                sp += 2 * USHB;
#pragma unroll
                for (int mt = 0; mt < 4; ++mt) {
                    bf16x8 av = *(const bf16x8*)(Asb + arow_b + mt * (16 * HBS * 2) + kt * 64);
                    a0[mt] = MF(av, b4, a0[mt]);
                    a1[mt] = MF(av, b5, a1[mt]);
                }
            }
            const int r0h = (l >> 4) * 4, m0c = wv * 32 + lcol, m1c = wv * 32 + 16 + lcol;
#pragma unroll
            for (int mt = 0; mt < 4; ++mt)
#pragma unroll
                for (int e = 0; e < 4; ++e) {
                    int tr = mt * 16 + r0h + e;
                    m1s[tr * M1S + m0c] = f2bf(a0[mt][e] > 0.f ? a0[mt][e] : 0.f);
                    m1s[tr * M1S + m1c] = f2bf(a1[mt][e] > 0.f ? a1[mt][e] : 0.f);
                }
            __syncthreads();

            const int grp = tid >> 3, pl = tid & 7;
            const int gn = grp / 5, gj = grp - gn * 5;
            if (tid < 640) {
                float b2r = b2[gj];
                for (int rd = 0; rd < 4; ++rd) {
                    int tr = rd * 16 + gn;
                    float acc = 0.f;
#pragma unroll
                    for (int q = 0; q < 8; ++q) {
                        bf16x8 mv  = *(const bf16x8*)(&m1s[tr * M1S] + q * 64 + pl * 8);
                        bf16x8 wvv = *(const bf16x8*)(&w2s[gj * 512] + q * 64 + pl * 8);
#pragma unroll
                        for (int e = 0; e < 8; ++e)
                            acc += bf2f((unsigned short)mv[e]) * bf2f((unsigned short)wvv[e]);
                    }
                    acc += __shfl_xor(acc, 1);
                    acc += __shfl_xor(acc, 2);
                    acc += __shfl_xor(acc, 4);
                    if (pl == 0) {
                        size_t tok = tok0 + tr;       // n-major: tok = n*TC + tloc
                        int n    = (int)(tok >> tcl2);
                        int tloc = (int)(tok & (size_t)(TC - 1));
                        out[(size_t)n * 1280 + (size_t)(t0p + tloc) * 5 + gj] = acc + b2r;
                    }
                }
            }
        }
    }
}

extern "C" void kernel_launch(void* const* d_in, const int* in_sizes, int n_in,
                              void* d_out, int out_size, void* d_ws, size_t ws_size,
                              hipStream_t stream) {
    (void)in_sizes; (void)n_in; (void)out_size;
    const float* x   = (const float*)d_in[0];
    const float* Wih = (const float*)d_in[1];
    const float* Whh = (const float*)d_in[2];
    const float* bih = (const float*)d_in[3];
    const float* bhh = (const float*)d_in[4];
    const float* W1  = (const float*)d_in[5];
    const float* b1  = (const float*)d_in[6];
    const float* W2  = (const float*)d_in[7];
    const float* b2  = (const float*)d_in[8];
    char* ws8 = (char*)d_ws;
    float* o = (float*)d_out;

    prep_gates_i8<<<16, 1024, 0, stream>>>(Whh, ws8);
    prep_trailer<<<1, 1024, 0, stream>>>(Wih, bih, bhh, ws8);
    prep_w1<<<18, 1024, 0, stream>>>(W1, b1, ws8);

    // TC tier: need H_OFF_B + 2 * (2048*TC*256*2) bytes (v9 proved ws >= 72MB).
    int tcl2 = (ws_size >= H_OFF_B + 2ull * 2048ull * 32ull * 256ull * 2ull) ? 5 : 4;
    const int TC = 1 << tcl2;
    float* state = (float*)(ws8 + WEIGHTS_B);
    unsigned short* HhA = (unsigned short*)(ws8 + H_OFF_B);
    unsigned short* HhB = HhA + (size_t)2048 * TC * 256;

    for (int t0 = 0; t0 <= 256; t0 += TC)
        combo<<<256, 1024, 0, stream>>>(x, ws8, HhA, HhB, state, W2, b2, o, t0, tcl2);
}